// Round 2
// baseline (411.375 us; speedup 1.0000x reference)
//
#include <hip/hip_runtime.h>

#define NCLS   50000
#define NC4    12500      // NCLS/4
#define BATCH  128
#define PPARTS 6
#define NROWS  768        // PPARTS*BATCH
#define FD     1536       // PPARTS*256

__device__ __forceinline__ float wave_sum(float v) {
#pragma unroll
  for (int off = 32; off > 0; off >>= 1) v += __shfl_xor(v, off, 64);
  return v;
}

// ws layout (floats): [0..15] acc, [16..143] invF, [144..271] invG, [272..] D[2][128][128]
#define WS_INVF 16
#define WS_INVG 144
#define WS_D    272

// ---------------------------------------------------------- branchless chunk
__device__ __forceinline__ void chunk_update(float4 xv, float4 sv,
    float& m, float& e1, float& e2, float& sx, float& ss, float& ssl, float& ssx) {
  const float i3 = 1.0f / 3.0f;
  float cm = fmaxf(fmaxf(xv.x, xv.y), fmaxf(xv.z, xv.w));
  float nm = fmaxf(m, cm);
  float d0 = xv.x - nm, d1 = xv.y - nm, d2 = xv.z - nm, d3 = xv.w - nm;
  float r = m - nm;                       // <= 0; exp(0)==1 exactly when no new max
  e1 = fmaf(e1, __expf(r),
            (__expf(d0) + __expf(d1)) + (__expf(d2) + __expf(d3)));
  e2 = fmaf(e2, __expf(r * i3),
            (__expf(d0 * i3) + __expf(d1 * i3)) + (__expf(d2 * i3) + __expf(d3 * i3)));
  m = nm;
  sx += (xv.x + xv.y) + (xv.z + xv.w);
  ss += (sv.x + sv.y) + (sv.z + sv.w);
  ssl = fmaf(sv.x, __logf(sv.x), fmaf(sv.y, __logf(sv.y),
        fmaf(sv.z, __logf(sv.z), fmaf(sv.w, __logf(sv.w), ssl))));
  ssx = fmaf(sv.x, xv.x, fmaf(sv.y, xv.y,
        fmaf(sv.z, xv.z, fmaf(sv.w, xv.w, ssx))));
}

// ------------------------------------------------ fused CE + KL over big rows
// one block (512 thr) per (p,b) row; single streaming pass; branchless online max
__global__ __launch_bounds__(512) void big_rows_k(
    const float* __restrict__ X, const float* __restrict__ S,
    const float* __restrict__ W, const int* __restrict__ labels,
    float* __restrict__ acc) {
  const int row = blockIdx.x;
  const int b = row & (BATCH - 1);
  const int t = threadIdx.x;
  const size_t base = (size_t)row * NCLS;
  const float4* x4 = (const float4*)(X + base);
  const float4* s4 = (const float4*)(S + base);
  const float i3 = 1.0f / 3.0f;

  float x_lab = (t == 0) ? X[base + labels[b]] : 0.0f;

  float m = -1e30f, e1 = 0.0f, e2 = 0.0f;
  float sx = 0.0f, ss = 0.0f, ssl = 0.0f, ssx = 0.0f;

  // 24 uniform chunks per thread (covers 12288), then tail of 212
#pragma unroll 4
  for (int k = 0; k < 24; ++k) {
    int i = t + (k << 9);
    chunk_update(x4[i], s4[i], m, e1, e2, sx, ss, ssl, ssx);
  }
  {
    int i = 12288 + t;
    if (i < NC4) chunk_update(x4[i], s4[i], m, e1, e2, sx, ss, ssl, ssx);
  }

  // wave reduction with max-rescale
#pragma unroll
  for (int off = 32; off > 0; off >>= 1) {
    float mo  = __shfl_xor(m, off, 64);
    float e1o = __shfl_xor(e1, off, 64);
    float e2o = __shfl_xor(e2, off, 64);
    float nm = fmaxf(m, mo);
    e1 = e1 * __expf(m - nm) + e1o * __expf(mo - nm);
    e2 = e2 * __expf((m - nm) * i3) + e2o * __expf((mo - nm) * i3);
    m = nm;
    sx  += __shfl_xor(sx, off, 64);
    ss  += __shfl_xor(ss, off, 64);
    ssl += __shfl_xor(ssl, off, 64);
    ssx += __shfl_xor(ssx, off, 64);
  }

  __shared__ float rm[8], re1[8], re2[8], rsx[8], rss[8], rssl[8], rssx[8];
  const int lane = t & 63, wid = t >> 6;
  if (lane == 0) {
    rm[wid] = m; re1[wid] = e1; re2[wid] = e2;
    rsx[wid] = sx; rss[wid] = ss; rssl[wid] = ssl; rssx[wid] = ssx;
  }
  __syncthreads();
  if (t == 0) {
    float M = rm[0], E1 = re1[0], E2 = re2[0];
#pragma unroll
    for (int wv = 1; wv < 8; ++wv) {
      float nm = fmaxf(M, rm[wv]);
      E1 = E1 * __expf(M - nm) + re1[wv] * __expf(rm[wv] - nm);
      E2 = E2 * __expf((M - nm) * i3) + re2[wv] * __expf((rm[wv] - nm) * i3);
      M = nm;
    }
    float SX = 0.f, SS = 0.f, SSL = 0.f, SSX = 0.f;
#pragma unroll
    for (int wv = 0; wv < 8; ++wv) { SX += rsx[wv]; SS += rss[wv]; SSL += rssl[wv]; SSX += rssx[wv]; }
    float logZ  = M + __logf(E1);
    float logZT = M * i3 + __logf(E2);
    float ce = 0.9f * (logZ - x_lab) + 0.1f * (logZ - SX * (1.0f / NCLS));
    float kl = SSL - SSX * i3 + logZT * SS;
    kl = fminf(kl, 5.0f);
    atomicAdd(&acc[0], ce);
    atomicAdd(&acc[1], kl * W[row]);
  }
}

// ------------------------------------- inverse norms of concat features + zero
// grid 256: [src(2) x batch(128)]
__global__ __launch_bounds__(256) void norm_k(
    const float* __restrict__ idf, const float* __restrict__ grayf,
    float* __restrict__ ws) {
  const int src = blockIdx.x >> 7;
  const int b = blockIdx.x & (BATCH - 1);
  const int t = threadIdx.x;
  const float* in = src ? grayf : idf;
  float sq = 0.0f;
#pragma unroll
  for (int k = 0; k < 6; ++k) {
    float v = in[((k * BATCH + b) << 8) + t];
    sq = fmaf(v, v, sq);
  }
  sq = wave_sum(sq);
  __shared__ float w4[4];
  const int lane = t & 63, wid = t >> 6;
  if (lane == 0) w4[wid] = sq;
  __syncthreads();
  if (t == 0)
    ws[16 + src * BATCH + b] = 1.0f / sqrtf(w4[0] + w4[1] + w4[2] + w4[3]);
  if (blockIdx.x == 0 && t < 16) ws[t] = 0.0f;   // zero accumulators
}

// --------------------------------------------- pairwise distances (32x32 tiles)
// reads RAW part-major features + inv norms; grid (4,4,2), block 256
__global__ __launch_bounds__(256) void dist_k(
    const float* __restrict__ idf, const float* __restrict__ grayf,
    float* __restrict__ ws) {
  const int z = blockIdx.z;
  const float* Bm = z ? grayf : idf;
  const float* invJsrc = ws + (z ? WS_INVG : WS_INVF);
  const float* invIsrc = ws + WS_INVF;
  float* D = ws + WS_D + z * BATCH * BATCH;
  const int i0 = blockIdx.y * 32, j0 = blockIdx.x * 32;
  const int t = threadIdx.x;

  __shared__ float As[32][33], Bs[32][33];
  __shared__ float sInvI[32], sInvJ[32];
  if (t < 32) sInvI[t] = invIsrc[i0 + t];
  else if (t < 64) sInvJ[t - 32] = invJsrc[j0 + t - 32];

  const int lr = t >> 3, lk = (t & 7) << 2;   // load: row 0..31, k-offset 0..28
  const int ty = t >> 4, tx = t & 15;         // compute: 2x2 outputs

  float c00 = 0.f, c01 = 0.f, c10 = 0.f, c11 = 0.f;
  for (int k0 = 0; k0 < FD; k0 += 32) {
    const int p = (k0 + lk) >> 8;             // part index (constant over tile)
    const int kin = (k0 + lk) & 255;
    float4 av = *(const float4*)&idf[((p * BATCH + i0 + lr) << 8) + kin];
    float4 bv = *(const float4*)&Bm [((p * BATCH + j0 + lr) << 8) + kin];
    As[lr][lk] = av.x; As[lr][lk+1] = av.y; As[lr][lk+2] = av.z; As[lr][lk+3] = av.w;
    Bs[lr][lk] = bv.x; Bs[lr][lk+1] = bv.y; Bs[lr][lk+2] = bv.z; Bs[lr][lk+3] = bv.w;
    __syncthreads();
#pragma unroll
    for (int k = 0; k < 32; ++k) {
      float a0 = As[2*ty][k],   a1 = As[2*ty+1][k];
      float b0 = Bs[2*tx][k],   b1 = Bs[2*tx+1][k];
      c00 = fmaf(a0, b0, c00);  c01 = fmaf(a0, b1, c01);
      c10 = fmaf(a1, b0, c10);  c11 = fmaf(a1, b1, c11);
    }
    __syncthreads();
  }
  float ii0 = sInvI[2*ty], ii1 = sInvI[2*ty+1];
  float jj0 = sInvJ[2*tx], jj1 = sInvJ[2*tx+1];
  float g00 = c00*ii0*jj0, g01 = c01*ii0*jj1, g10 = c10*ii1*jj0, g11 = c11*ii1*jj1;
  D[(i0+2*ty  )*BATCH + j0+2*tx  ] = sqrtf(fmaxf(2.f-2.f*g00, 0.f) + 1e-12f);
  D[(i0+2*ty  )*BATCH + j0+2*tx+1] = sqrtf(fmaxf(2.f-2.f*g01, 0.f) + 1e-12f);
  D[(i0+2*ty+1)*BATCH + j0+2*tx  ] = sqrtf(fmaxf(2.f-2.f*g10, 0.f) + 1e-12f);
  D[(i0+2*ty+1)*BATCH + j0+2*tx+1] = sqrtf(fmaxf(2.f-2.f*g11, 0.f) + 1e-12f);
}

// ------------------------------------- fused mine + adversarial CE + combine
__global__ __launch_bounds__(256) void tail_k(
    const float* __restrict__ ws_c, const float* __restrict__ advl,
    const int* __restrict__ labels, const int* __restrict__ mod,
    const int* __restrict__ epoch, float* __restrict__ out) {
  const int t = threadIdx.x;
  __shared__ int slab[BATCH];
  __shared__ float red[8];
  if (t < BATCH) slab[t] = labels[t];
  __syncthreads();

  // --- hard mining: threads 0..127 -> D0 (same), 128..255 -> D1 (trans)
  const int z = t >> 7;
  const int b = t & (BATCH - 1);
  const int lb = slab[b];
  const float* drow = ws_c + WS_D + z * BATCH * BATCH + b * BATCH;
  float ap = -1e30f, an = 1e30f;
  int hasp = 0, hasn = 0;
#pragma unroll 4
  for (int j = 0; j < BATCH; ++j) {
    bool eq = (slab[j] == lb);
    float v = drow[j];
    bool posok = eq && (z == 1 || j != b);
    if (posok) { hasp = 1; ap = fmaxf(ap, v); }
    if (!eq)   { hasn = 1; an = fminf(an, v); }
  }
  float dap = hasp ? ap : 0.0f;
  float dan = hasn ? an : 1e6f;
  float hinge = fmaxf(dap - dan + 0.3f, 0.0f);
  hinge = wave_sum(hinge);   // waves 0,1 -> z0 ; waves 2,3 -> z1

  // --- adversarial CE: all 256 threads, 3 rows each
  float advs = 0.0f;
#pragma unroll
  for (int k = 0; k < 3; ++k) {
    int r = t + (k << 8);
    int rb = r & (BATCH - 1);
    float l0 = advl[2 * r], l1 = advl[2 * r + 1];
    float mx = fmaxf(l0, l1);
    float lse = mx + __logf(__expf(l0 - mx) + __expf(l1 - mx));
    advs += lse - (mod[rb] ? l1 : l0);
  }
  advs = wave_sum(advs);

  const int lane = t & 63, wid = t >> 6;
  if (lane == 0) { red[wid] = hinge; red[4 + wid] = advs; }
  __syncthreads();
  if (t == 0) {
    float tri1 = red[0] + red[1];
    float tri2 = red[2] + red[3];
    float adv  = red[4] + red[5] + red[6] + red[7];
    float L_id  = ws_c[0] * (1.0f / NROWS);
    float L_tri = tri1 * (1.0f / BATCH) + 0.5f * tri2 * (1.0f / BATCH);
    float L_graph = (epoch[0] >= 20) ? ws_c[1] * (9.0f / 768.0f) : 0.0f;
    float L_adv = adv * (1.0f / NROWS);
    out[0] = L_id + L_tri + 0.1f * L_graph + 0.1f * L_adv;
  }
}

extern "C" void kernel_launch(void* const* d_in, const int* in_sizes, int n_in,
                              void* d_out, int out_size, void* d_ws, size_t ws_size,
                              hipStream_t stream) {
  (void)in_sizes; (void)n_in; (void)out_size; (void)ws_size;
  const float* id_logits = (const float*)d_in[0];
  const float* id_feat   = (const float*)d_in[1];
  const float* gray_feat = (const float*)d_in[2];
  const float* soft      = (const float*)d_in[3];
  const float* entw      = (const float*)d_in[4];
  const float* advl      = (const float*)d_in[5];
  const int*   labels    = (const int*)d_in[6];
  const int*   modality  = (const int*)d_in[7];
  const int*   epoch     = (const int*)d_in[8];
  float* out = (float*)d_out;
  float* ws = (float*)d_ws;

  norm_k<<<256, 256, 0, stream>>>(id_feat, gray_feat, ws);
  dist_k<<<dim3(4, 4, 2), 256, 0, stream>>>(id_feat, gray_feat, ws);
  big_rows_k<<<NROWS, 512, 0, stream>>>(id_logits, soft, entw, labels, ws);
  tail_k<<<1, 256, 0, stream>>>(ws, advl, labels, modality, epoch, out);
}

// Round 4
// 409.183 us; speedup vs baseline: 1.0054x; 1.0054x over previous
//
#include <hip/hip_runtime.h>

#define NCLS   50000
#define NC4    12500      // NCLS/4
#define BATCH  128
#define PPARTS 6
#define NROWS  768        // PPARTS*BATCH
#define FD     1536       // PPARTS*256

__device__ __forceinline__ float wave_sum(float v) {
#pragma unroll
  for (int off = 32; off > 0; off >>= 1) v += __shfl_xor(v, off, 64);
  return v;
}

// direct gfx950 transcendental codegen: v_exp_f32 is 2^x, v_log_f32 is log2(x)
__device__ __forceinline__ float fexp2(float x) { return __builtin_amdgcn_exp2f(x); }
__device__ __forceinline__ float flog2(float x) { return __builtin_amdgcn_logf(x); }

// ws layout (floats): [0..15] acc, [16..143] invF, [144..271] invG, [272..] D[2][128][128]
#define WS_INVF 16
#define WS_INVG 144
#define WS_D    272

#define LOG2E 1.4426950408889634f
#define LN2   0.6931471805599453f

// ---------------------------------------------------------- branchless chunk
// exp(x) computed as exp2(x*log2e); log(s) as log2(s)*ln2 (ln2 folded at end)
__device__ __forceinline__ void chunk_update(float4 xv, float4 sv,
    float& m, float& e1, float& e2, float& sx, float& ss, float& ssl, float& ssx) {
  const float L1 = LOG2E;
  const float L3 = LOG2E / 3.0f;
  float cm = fmaxf(fmaxf(xv.x, xv.y), fmaxf(xv.z, xv.w));
  float nm = fmaxf(m, cm);
  float r  = m - nm;                      // <= 0; exp2(0)==1 exactly when no new max
  float d0 = xv.x - nm, d1 = xv.y - nm, d2 = xv.z - nm, d3 = xv.w - nm;
  e1 = fmaf(e1, fexp2(r * L1),
            (fexp2(d0 * L1) + fexp2(d1 * L1)) + (fexp2(d2 * L1) + fexp2(d3 * L1)));
  e2 = fmaf(e2, fexp2(r * L3),
            (fexp2(d0 * L3) + fexp2(d1 * L3)) + (fexp2(d2 * L3) + fexp2(d3 * L3)));
  m = nm;
  sx += (xv.x + xv.y) + (xv.z + xv.w);
  ss += (sv.x + sv.y) + (sv.z + sv.w);
  ssl = fmaf(sv.x, flog2(sv.x), fmaf(sv.y, flog2(sv.y),
        fmaf(sv.z, flog2(sv.z), fmaf(sv.w, flog2(sv.w), ssl))));
  ssx = fmaf(sv.x, xv.x, fmaf(sv.y, xv.y,
        fmaf(sv.z, xv.z, fmaf(sv.w, xv.w, ssx))));
}

// ------------------------------------------------ fused CE + KL over big rows
// one block (512 thr) per (p,b) row; batched register prefetch for MLP:
// 8 independent dwordx4 loads (128B/lane in flight) before any compute.
__global__ __launch_bounds__(512) void big_rows_k(
    const float* __restrict__ X, const float* __restrict__ S,
    const float* __restrict__ W, const int* __restrict__ labels,
    float* __restrict__ acc) {
  const int row = blockIdx.x;
  const int b = row & (BATCH - 1);
  const int t = threadIdx.x;
  const size_t base = (size_t)row * NCLS;
  const float4* x4 = (const float4*)(X + base);
  const float4* s4 = (const float4*)(S + base);
  const float i3 = 1.0f / 3.0f;

  float x_lab = (t == 0) ? X[base + labels[b]] : 0.0f;

  float m = -1e30f, e1 = 0.0f, e2 = 0.0f;
  float sx = 0.0f, ss = 0.0f, ssl = 0.0f, ssx = 0.0f;

  // 24 chunks/thread = 6 outer x 4 batched (covers 12288), then tail of 212
  float4 xr[4], sr[4];
#pragma unroll 1
  for (int outer = 0; outer < 6; ++outer) {
    const int i0 = t + (outer << 11);         // outer * 2048
#pragma unroll
    for (int j = 0; j < 4; ++j) {             // 8 independent loads, no compute between
      xr[j] = x4[i0 + (j << 9)];
      sr[j] = s4[i0 + (j << 9)];
    }
#pragma unroll
    for (int j = 0; j < 4; ++j)
      chunk_update(xr[j], sr[j], m, e1, e2, sx, ss, ssl, ssx);
  }
  {
    int i = 12288 + t;
    if (i < NC4) chunk_update(x4[i], s4[i], m, e1, e2, sx, ss, ssl, ssx);
  }

  // wave reduction with max-rescale
#pragma unroll
  for (int off = 32; off > 0; off >>= 1) {
    float mo  = __shfl_xor(m, off, 64);
    float e1o = __shfl_xor(e1, off, 64);
    float e2o = __shfl_xor(e2, off, 64);
    float nm = fmaxf(m, mo);
    e1 = e1 * __expf(m - nm) + e1o * __expf(mo - nm);
    e2 = e2 * __expf((m - nm) * i3) + e2o * __expf((mo - nm) * i3);
    m = nm;
    sx  += __shfl_xor(sx, off, 64);
    ss  += __shfl_xor(ss, off, 64);
    ssl += __shfl_xor(ssl, off, 64);
    ssx += __shfl_xor(ssx, off, 64);
  }

  __shared__ float rm[8], re1[8], re2[8], rsx[8], rss[8], rssl[8], rssx[8];
  const int lane = t & 63, wid = t >> 6;
  if (lane == 0) {
    rm[wid] = m; re1[wid] = e1; re2[wid] = e2;
    rsx[wid] = sx; rss[wid] = ss; rssl[wid] = ssl; rssx[wid] = ssx;
  }
  __syncthreads();
  if (t == 0) {
    float M = rm[0], E1 = re1[0], E2 = re2[0];
#pragma unroll
    for (int wv = 1; wv < 8; ++wv) {
      float nm = fmaxf(M, rm[wv]);
      E1 = E1 * __expf(M - nm) + re1[wv] * __expf(rm[wv] - nm);
      E2 = E2 * __expf((M - nm) * i3) + re2[wv] * __expf((rm[wv] - nm) * i3);
      M = nm;
    }
    float SX = 0.f, SS = 0.f, SSL = 0.f, SSX = 0.f;
#pragma unroll
    for (int wv = 0; wv < 8; ++wv) { SX += rsx[wv]; SS += rss[wv]; SSL += rssl[wv]; SSX += rssx[wv]; }
    SSL *= LN2;                                   // log2 -> ln
    float logZ  = M + __logf(E1);
    float logZT = M * i3 + __logf(E2);
    float ce = 0.9f * (logZ - x_lab) + 0.1f * (logZ - SX * (1.0f / NCLS));
    float kl = SSL - SSX * i3 + logZT * SS;
    kl = fminf(kl, 5.0f);
    atomicAdd(&acc[0], ce);
    atomicAdd(&acc[1], kl * W[row]);
  }
}

// ------------------------------------- inverse norms of concat features + zero
// grid 256: [src(2) x batch(128)]
__global__ __launch_bounds__(256) void norm_k(
    const float* __restrict__ idf, const float* __restrict__ grayf,
    float* __restrict__ ws) {
  const int src = blockIdx.x >> 7;
  const int b = blockIdx.x & (BATCH - 1);
  const int t = threadIdx.x;
  const float* in = src ? grayf : idf;
  float sq = 0.0f;
#pragma unroll
  for (int k = 0; k < 6; ++k) {
    float v = in[((k * BATCH + b) << 8) + t];
    sq = fmaf(v, v, sq);
  }
  sq = wave_sum(sq);
  __shared__ float w4[4];
  const int lane = t & 63, wid = t >> 6;
  if (lane == 0) w4[wid] = sq;
  __syncthreads();
  if (t == 0)
    ws[16 + src * BATCH + b] = 1.0f / sqrtf(w4[0] + w4[1] + w4[2] + w4[3]);
  if (blockIdx.x == 0 && t < 16) ws[t] = 0.0f;   // zero accumulators
}

// --------------------------------------------- pairwise distances (32x32 tiles)
// reads RAW part-major features + inv norms; grid (4,4,2), block 256
__global__ __launch_bounds__(256) void dist_k(
    const float* __restrict__ idf, const float* __restrict__ grayf,
    float* __restrict__ ws) {
  const int z = blockIdx.z;
  const float* Bm = z ? grayf : idf;
  const float* invJsrc = ws + (z ? WS_INVG : WS_INVF);
  const float* invIsrc = ws + WS_INVF;
  float* D = ws + WS_D + z * BATCH * BATCH;
  const int i0 = blockIdx.y * 32, j0 = blockIdx.x * 32;
  const int t = threadIdx.x;

  __shared__ float As[32][33], Bs[32][33];
  __shared__ float sInvI[32], sInvJ[32];
  if (t < 32) sInvI[t] = invIsrc[i0 + t];
  else if (t < 64) sInvJ[t - 32] = invJsrc[j0 + t - 32];

  const int lr = t >> 3, lk = (t & 7) << 2;   // load: row 0..31, k-offset 0..28
  const int ty = t >> 4, tx = t & 15;         // compute: 2x2 outputs

  float c00 = 0.f, c01 = 0.f, c10 = 0.f, c11 = 0.f;
  for (int k0 = 0; k0 < FD; k0 += 32) {
    const int p = (k0 + lk) >> 8;             // part index (constant over tile)
    const int kin = (k0 + lk) & 255;
    float4 av = *(const float4*)&idf[((p * BATCH + i0 + lr) << 8) + kin];
    float4 bv = *(const float4*)&Bm [((p * BATCH + j0 + lr) << 8) + kin];
    As[lr][lk] = av.x; As[lr][lk+1] = av.y; As[lr][lk+2] = av.z; As[lr][lk+3] = av.w;
    Bs[lr][lk] = bv.x; Bs[lr][lk+1] = bv.y; Bs[lr][lk+2] = bv.z; Bs[lr][lk+3] = bv.w;
    __syncthreads();
#pragma unroll
    for (int k = 0; k < 32; ++k) {
      float a0 = As[2*ty][k],   a1 = As[2*ty+1][k];
      float b0 = Bs[2*tx][k],   b1 = Bs[2*tx+1][k];
      c00 = fmaf(a0, b0, c00);  c01 = fmaf(a0, b1, c01);
      c10 = fmaf(a1, b0, c10);  c11 = fmaf(a1, b1, c11);
    }
    __syncthreads();
  }
  float ii0 = sInvI[2*ty], ii1 = sInvI[2*ty+1];
  float jj0 = sInvJ[2*tx], jj1 = sInvJ[2*tx+1];
  float g00 = c00*ii0*jj0, g01 = c01*ii0*jj1, g10 = c10*ii1*jj0, g11 = c11*ii1*jj1;
  D[(i0+2*ty  )*BATCH + j0+2*tx  ] = sqrtf(fmaxf(2.f-2.f*g00, 0.f) + 1e-12f);
  D[(i0+2*ty  )*BATCH + j0+2*tx+1] = sqrtf(fmaxf(2.f-2.f*g01, 0.f) + 1e-12f);
  D[(i0+2*ty+1)*BATCH + j0+2*tx  ] = sqrtf(fmaxf(2.f-2.f*g10, 0.f) + 1e-12f);
  D[(i0+2*ty+1)*BATCH + j0+2*tx+1] = sqrtf(fmaxf(2.f-2.f*g11, 0.f) + 1e-12f);
}

// ------------------------------------- fused mine + adversarial CE + combine
__global__ __launch_bounds__(256) void tail_k(
    const float* __restrict__ ws_c, const float* __restrict__ advl,
    const int* __restrict__ labels, const int* __restrict__ mod,
    const int* __restrict__ epoch, float* __restrict__ out) {
  const int t = threadIdx.x;
  __shared__ int slab[BATCH];
  __shared__ float red[8];
  if (t < BATCH) slab[t] = labels[t];
  __syncthreads();

  // --- hard mining: threads 0..127 -> D0 (same), 128..255 -> D1 (trans)
  const int z = t >> 7;
  const int b = t & (BATCH - 1);
  const int lb = slab[b];
  const float* drow = ws_c + WS_D + z * BATCH * BATCH + b * BATCH;
  float ap = -1e30f, an = 1e30f;
  int hasp = 0, hasn = 0;
#pragma unroll 4
  for (int j = 0; j < BATCH; ++j) {
    bool eq = (slab[j] == lb);
    float v = drow[j];
    bool posok = eq && (z == 1 || j != b);
    if (posok) { hasp = 1; ap = fmaxf(ap, v); }
    if (!eq)   { hasn = 1; an = fminf(an, v); }
  }
  float dap = hasp ? ap : 0.0f;
  float dan = hasn ? an : 1e6f;
  float hinge = fmaxf(dap - dan + 0.3f, 0.0f);
  hinge = wave_sum(hinge);   // waves 0,1 -> z0 ; waves 2,3 -> z1

  // --- adversarial CE: all 256 threads, 3 rows each
  float advs = 0.0f;
#pragma unroll
  for (int k = 0; k < 3; ++k) {
    int r = t + (k << 8);
    int rb = r & (BATCH - 1);
    float l0 = advl[2 * r], l1 = advl[2 * r + 1];
    float mx = fmaxf(l0, l1);
    float lse = mx + __logf(__expf(l0 - mx) + __expf(l1 - mx));
    advs += lse - (mod[rb] ? l1 : l0);
  }
  advs = wave_sum(advs);

  const int lane = t & 63, wid = t >> 6;
  if (lane == 0) { red[wid] = hinge; red[4 + wid] = advs; }
  __syncthreads();
  if (t == 0) {
    float tri1 = red[0] + red[1];
    float tri2 = red[2] + red[3];
    float adv  = red[4] + red[5] + red[6] + red[7];
    float L_id  = ws_c[0] * (1.0f / NROWS);
    float L_tri = tri1 * (1.0f / BATCH) + 0.5f * tri2 * (1.0f / BATCH);
    float L_graph = (epoch[0] >= 20) ? ws_c[1] * (9.0f / 768.0f) : 0.0f;
    float L_adv = adv * (1.0f / NROWS);
    out[0] = L_id + L_tri + 0.1f * L_graph + 0.1f * L_adv;
  }
}

extern "C" void kernel_launch(void* const* d_in, const int* in_sizes, int n_in,
                              void* d_out, int out_size, void* d_ws, size_t ws_size,
                              hipStream_t stream) {
  (void)in_sizes; (void)n_in; (void)out_size; (void)ws_size;
  const float* id_logits = (const float*)d_in[0];
  const float* id_feat   = (const float*)d_in[1];
  const float* gray_feat = (const float*)d_in[2];
  const float* soft      = (const float*)d_in[3];
  const float* entw      = (const float*)d_in[4];
  const float* advl      = (const float*)d_in[5];
  const int*   labels    = (const int*)d_in[6];
  const int*   modality  = (const int*)d_in[7];
  const int*   epoch     = (const int*)d_in[8];
  float* out = (float*)d_out;
  float* ws = (float*)d_ws;

  norm_k<<<256, 256, 0, stream>>>(id_feat, gray_feat, ws);
  dist_k<<<dim3(4, 4, 2), 256, 0, stream>>>(id_feat, gray_feat, ws);
  big_rows_k<<<NROWS, 512, 0, stream>>>(id_logits, soft, entw, labels, ws);
  tail_k<<<1, 256, 0, stream>>>(ws, advl, labels, modality, epoch, out);
}